// Round 6
// baseline (912.100 us; speedup 1.0000x reference)
//
#include <hip/hip_runtime.h>
#include <hip/hip_bf16.h>

// GCN_5016521802361: 2x SAGEConv(aggr='lstm', project=True), N=50000, D=16, F=128, C=40.
// Round 6: amortize the per-step stall (barrier skew + chain exposure, ~1500cy measured
// via r5 counters) over 2x work: 32 nodes/block in two groups A/B processed within one
// barrier interval, acc registers reused A->B, Y-prefetch double-buffer reinterpreted
// as bufA/bufB (register-neutral; only +8 VGPR for second c-state -> no spill).
// Plus rcp-merged gate math: sigm*tanh products share one reciprocal (5exp+3rcp vs 5+5).

typedef __hip_bfloat16 bf16;
typedef __attribute__((ext_vector_type(8))) short short8;
typedef __attribute__((ext_vector_type(4))) short short4v;
typedef __attribute__((ext_vector_type(4))) float floatx4;

__device__ __forceinline__ float bf2f(bf16 v) { return __bfloat162float(v); }
__device__ __forceinline__ bf16  f2bf(float v) { return __float2bfloat16(v); }
__device__ __forceinline__ float bfs2f(short s) {
    union { float f; unsigned u; } v; v.u = ((unsigned)(unsigned short)s) << 16; return v.f;
}
__device__ __forceinline__ short f2bfs(float v) {
    bf16 b = __float2bfloat16(v); return *(short*)&b;
}

// merged-rcp LSTM cell update: c' = sigm(f)c + sigm(i)tanh(g); h' = sigm(o)tanh(c')
// sigm(i)tanh(g) = (e^2g - 1) * rcp((1+e^-i)(e^2g + 1));  5 exp + 3 rcp total.
__device__ __forceinline__ float cell(float i_, float f_, float g_, float o_, float& c) {
    float ei = __expf(-i_), ef = __expf(-f_), eg = __expf(2.f * g_);
    float cn = c * __builtin_amdgcn_rcpf(1.f + ef)
             + (eg - 1.f) * __builtin_amdgcn_rcpf((1.f + ei) * (eg + 1.f));
    c = cn;
    float ec = __expf(2.f * cn), eo = __expf(-o_);
    return (ec - 1.f) * __builtin_amdgcn_rcpf((ec + 1.f) * (1.f + eo));
}

// barrier that does NOT drain vmcnt (LDS-only ordering)
__device__ __forceinline__ void sync_lds_only() {
    asm volatile("s_waitcnt lgkmcnt(0)\n\ts_barrier" ::: "memory");
}

__global__ void detect_dtype(const unsigned short* __restrict__ xb, int* __restrict__ flag) {
    int cnt = 0;
    for (int i = threadIdx.x; i < 1024; i += 64) {
        int e = (xb[i] >> 7) & 0xFF;
        cnt += (e >= 0xC8);   // impossible exponent for N(0,1) bf16 data
    }
#pragma unroll
    for (int off = 32; off; off >>= 1) cnt += __shfl_down(cnt, off);
    if (threadIdx.x == 0) *flag = (cnt >= 16) ? 1 : 0;   // 1 => inputs are float32
}

struct Cvt { const void* src; bf16* dst; int n; };
struct CvtAll { Cvt t[19]; };

__global__ void convert_inputs(CvtAll ca, const int* __restrict__ flag) {
    const bool isf32 = (*flag != 0);
    const int stride = gridDim.x * blockDim.x;
    const int tid0 = blockIdx.x * blockDim.x + threadIdx.x;
#pragma unroll 1
    for (int k = 0; k < 19; k++) {
        const int n = ca.t[k].n;
        const float* sf = (const float*)ca.t[k].src;
        const bf16*  sb = (const bf16*)ca.t[k].src;
        bf16* d = ca.t[k].dst;
        for (int i = tid0; i < n; i += stride)
            d[i] = isf32 ? f2bf(sf[i]) : sb[i];
    }
}

template <int NCT, bool RELU, bool BIAS2, bool DUAL, bool OUTF>
__global__ __launch_bounds__(256, 1) void gemm_bias(
    const bf16* __restrict__ A, const bf16* __restrict__ B,
    const bf16* __restrict__ bias, const bf16* __restrict__ bias2,
    const bf16* __restrict__ A2, const bf16* __restrict__ B2,
    void* __restrict__ Cv, const int* __restrict__ oflag,
    int N, int nbt, int ldc)
{
    const int tid = threadIdx.x;
    const int w = tid >> 6, l = tid & 63, q = l >> 4, lid = l & 15;
    const int rowbase = blockIdx.x * 64 + w * 16;
    const int colslice = blockIdx.y * 128;

    int arow = rowbase + lid;
    if (arow >= N) arow = N - 1;

    floatx4 acc[NCT];
#pragma unroll
    for (int ct = 0; ct < NCT; ct++) acc[ct] = (floatx4)(0.f);

    short8 bfrag[NCT][4];
#pragma unroll
    for (int ct = 0; ct < NCT; ct++) {
        int j = colslice + ct * 16 + lid;
        if (j >= nbt) j = nbt - 1;
#pragma unroll
        for (int kt = 0; kt < 4; kt++)
            bfrag[ct][kt] = *(const short8*)(B + (size_t)j * 128 + kt * 32 + q * 8);
    }
#pragma unroll
    for (int kt = 0; kt < 4; kt++) {
        short8 af = *(const short8*)(A + (size_t)arow * 128 + kt * 32 + q * 8);
#pragma unroll
        for (int ct = 0; ct < NCT; ct++)
            acc[ct] = __builtin_amdgcn_mfma_f32_16x16x32_bf16(af, bfrag[ct][kt], acc[ct], 0, 0, 0);
    }
    if constexpr (DUAL) {
#pragma unroll
        for (int ct = 0; ct < NCT; ct++) {
            int j = colslice + ct * 16 + lid;
            if (j >= nbt) j = nbt - 1;
#pragma unroll
            for (int kt = 0; kt < 4; kt++)
                bfrag[ct][kt] = *(const short8*)(B2 + (size_t)j * 128 + kt * 32 + q * 8);
        }
#pragma unroll
        for (int kt = 0; kt < 4; kt++) {
            short8 af = *(const short8*)(A2 + (size_t)arow * 128 + kt * 32 + q * 8);
#pragma unroll
            for (int ct = 0; ct < NCT; ct++)
                acc[ct] = __builtin_amdgcn_mfma_f32_16x16x32_bf16(af, bfrag[ct][kt], acc[ct], 0, 0, 0);
        }
    }
    bool of32 = false;
    if constexpr (OUTF) of32 = (*oflag != 0);
#pragma unroll
    for (int ct = 0; ct < NCT; ct++) {
        int cg = colslice + ct * 16 + lid;
        int cb = cg < nbt ? cg : nbt - 1;
        float bv = bf2f(bias[cb]);
        if constexpr (BIAS2) bv += bf2f(bias2[cb]);
#pragma unroll
        for (int r = 0; r < 4; r++) {
            int row = rowbase + q * 4 + r;
            float v = acc[ct][r] + bv;
            if constexpr (RELU) v = fmaxf(v, 0.f);
            if (row < N && cg < nbt) {
                size_t idx = (size_t)row * ldc + cg;
                if constexpr (OUTF) {
                    if (of32) ((float*)Cv)[idx] = v;
                    else      ((bf16*)Cv)[idx] = f2bf(v);
                } else {
                    ((bf16*)Cv)[idx] = f2bf(v);
                }
            }
        }
    }
}

// ---------------------------------------------------------------------------
// LSTM neighbor aggregation, transposed recurrence G^T = Whh * h^T.
// Block = 32 nodes (groups A: lid, B: 16+lid), 256 thr (4 waves).
// Wave w owns hidden cols [32w,32w+32); Whh A-frags register-resident (128 regs,
// shared by both groups); h via LDS; c in regs (2 groups). Y gather: 8 dwordx2
// per thread per group per step; bufA/bufB double-buffer, refilled right after
// consumption so loads stay in flight ~a full step. One lgkm-only barrier per
// step covers both groups -> fixed per-step overhead amortized over 2x nodes.
// ---------------------------------------------------------------------------
__global__ __launch_bounds__(256, 2) void lstm_aggr(
    const bf16* __restrict__ Y,     // [N,512] pre-activations incl. both biases
    const int* __restrict__ esrc,   // [N,16]
    const bf16* __restrict__ Whh,   // [512,128]
    bf16* __restrict__ aggr,        // [N,128] out: final h
    int N)
{
    __shared__ alignas(16) bf16 hb[2][32][136];
    __shared__ int srcl[16][32];    // [t][node 0..31]

    const int tid = threadIdx.x;
    const int w = tid >> 6, l = tid & 63, q = l >> 4, lid = l & 15;
    const int nodebase = blockIdx.x * 32;

    for (int i = tid; i < 512; i += 256) {
        int node = i >> 4, t = i & 15;
        int gn = nodebase + node; if (gn >= N) gn = N - 1;
        srcl[t][node] = esrc[(size_t)gn * 16 + t];
    }
    for (int i = tid; i < 32 * 136; i += 256) ((short*)hb[0])[i] = 0;

    // Whh A-fragments: wf[hl][g][kt]; A-row = gatecol = (2w+hl+8g)*16 + lid
    short8 wf[2][4][4];
#pragma unroll
    for (int hl = 0; hl < 2; hl++)
#pragma unroll
        for (int g = 0; g < 4; g++) {
            int gc = (2 * w + hl + 8 * g) * 16 + lid;
#pragma unroll
            for (int kt = 0; kt < 4; kt++)
                wf[hl][g][kt] = *(const short8*)(Whh + (size_t)gc * 128 + kt * 32 + q * 8);
        }

    float cA[2][4], cB[2][4];
#pragma unroll
    for (int hl = 0; hl < 2; hl++)
#pragma unroll
        for (int r = 0; r < 4; r++) { cA[hl][r] = 0.f; cB[hl][r] = 0.f; }

    __syncthreads();   // full sync once: srcl/hb visible before preload

    // Y prefetch buffers: yA for group A (node lid), yB for group B (node 16+lid)
    short4v yA[2][4], yB[2][4];
    {
        int sa = srcl[0][lid];
        const bf16* yb = Y + (size_t)sa * 512 + q * 4;
#pragma unroll
        for (int hl = 0; hl < 2; hl++)
#pragma unroll
            for (int g = 0; g < 4; g++)
                yA[hl][g] = *(const short4v*)(yb + (2 * w + hl + 8 * g) * 16);
        int sb = srcl[0][16 + lid];
        const bf16* yc = Y + (size_t)sb * 512 + q * 4;
#pragma unroll
        for (int hl = 0; hl < 2; hl++)
#pragma unroll
            for (int g = 0; g < 4; g++)
                yB[hl][g] = *(const short4v*)(yc + (2 * w + hl + 8 * g) * 16);
    }

#pragma unroll 2
    for (int t = 0; t < 16; t++) {
        const int cur = t & 1, nxt = cur ^ 1;
        floatx4 acc[2][4];

        // ================= group A (nodes nodebase + lid) =================
#pragma unroll
        for (int hl = 0; hl < 2; hl++)
#pragma unroll
            for (int g = 0; g < 4; g++)
#pragma unroll
                for (int r = 0; r < 4; r++)
                    acc[hl][g][r] = bfs2f(yA[hl][g][r]);

        if (t < 15) {   // refill A for t+1; stays in flight across the barrier
            int sa = srcl[t + 1][lid];
            const bf16* yb = Y + (size_t)sa * 512 + q * 4;
#pragma unroll
            for (int hl = 0; hl < 2; hl++)
#pragma unroll
                for (int g = 0; g < 4; g++)
                    yA[hl][g] = *(const short4v*)(yb + (2 * w + hl + 8 * g) * 16);
        }

#pragma unroll
        for (int kt = 0; kt < 4; kt++) {
            short8 bh = *(const short8*)&hb[cur][lid][kt * 32 + q * 8];
#pragma unroll
            for (int hl = 0; hl < 2; hl++)
#pragma unroll
                for (int g = 0; g < 4; g++)
                    acc[hl][g] = __builtin_amdgcn_mfma_f32_16x16x32_bf16(wf[hl][g][kt], bh, acc[hl][g], 0, 0, 0);
        }

#pragma unroll
        for (int hl = 0; hl < 2; hl++) {
            short4v hv;
#pragma unroll
            for (int r = 0; r < 4; r++)
                hv[r] = f2bfs(cell(acc[hl][0][r], acc[hl][1][r], acc[hl][2][r], acc[hl][3][r], cA[hl][r]));
            if (t < 15) *(short4v*)&hb[nxt][lid][32 * w + 16 * hl + 4 * q] = hv;
            else        *(short4v*)(aggr + (size_t)(nodebase + lid) * 128 + 32 * w + 16 * hl + 4 * q) = hv;
        }

        // ================= group B (nodes nodebase + 16 + lid) =================
#pragma unroll
        for (int hl = 0; hl < 2; hl++)
#pragma unroll
            for (int g = 0; g < 4; g++)
#pragma unroll
                for (int r = 0; r < 4; r++)
                    acc[hl][g][r] = bfs2f(yB[hl][g][r]);

        if (t < 15) {
            int sb = srcl[t + 1][16 + lid];
            const bf16* yc = Y + (size_t)sb * 512 + q * 4;
#pragma unroll
            for (int hl = 0; hl < 2; hl++)
#pragma unroll
                for (int g = 0; g < 4; g++)
                    yB[hl][g] = *(const short4v*)(yc + (2 * w + hl + 8 * g) * 16);
        }

#pragma unroll
        for (int kt = 0; kt < 4; kt++) {
            short8 bh = *(const short8*)&hb[cur][16 + lid][kt * 32 + q * 8];
#pragma unroll
            for (int hl = 0; hl < 2; hl++)
#pragma unroll
                for (int g = 0; g < 4; g++)
                    acc[hl][g] = __builtin_amdgcn_mfma_f32_16x16x32_bf16(wf[hl][g][kt], bh, acc[hl][g], 0, 0, 0);
        }

#pragma unroll
        for (int hl = 0; hl < 2; hl++) {
            short4v hv;
#pragma unroll
            for (int r = 0; r < 4; r++)
                hv[r] = f2bfs(cell(acc[hl][0][r], acc[hl][1][r], acc[hl][2][r], acc[hl][3][r], cB[hl][r]));
            if (t < 15) {
                *(short4v*)&hb[nxt][16 + lid][32 * w + 16 * hl + 4 * q] = hv;
            } else {
                int gn = nodebase + 16 + lid;
                if (gn < N)
                    *(short4v*)(aggr + (size_t)gn * 128 + 32 * w + 16 * hl + 4 * q) = hv;
            }
        }

        sync_lds_only();   // one barrier per step covers both groups
    }
}

extern "C" void kernel_launch(void* const* d_in, const int* in_sizes, int n_in,
                              void* d_out, int out_size, void* d_ws, size_t ws_size,
                              hipStream_t stream)
{
    const int N = 50000;
    const int* es = (const int*)d_in[1];
    char* ws = (char*)d_ws;

    // converted bf16 copies of the 19 used float tensors @[0,15MB)
    static const int idxs[19] = {0, 8,9,10,11,12,13,14,15,16, 17,18,19,20,21,22,23,24,25};
    bf16* conv[19];
    size_t off = 0;
    CvtAll ca;
    for (int k = 0; k < 19; k++) {
        conv[k] = (bf16*)ws + off;
        ca.t[k].src = d_in[idxs[k]];
        ca.t[k].dst = conv[k];
        ca.t[k].n = in_sizes[idxs[k]];
        off += (size_t)((in_sizes[idxs[k]] + 63) & ~63);
    }
    int* flag = (int*)(ws + ((size_t)15 << 20));
    bf16* xp   = (bf16*)(ws + ((size_t)16 << 20));   // [N,128], reused as aggr
    bf16* Y    = (bf16*)(ws + ((size_t)30 << 20));   // [N,512]
    bf16* h1   = (bf16*)(ws + ((size_t)84 << 20));   // [N,128]
    bf16* aggr = xp;

    const bf16 *xc  = conv[0];
    const bf16 *Wp1 = conv[1],  *bp1 = conv[2],  *Wih1 = conv[3],  *Whh1 = conv[4];
    const bf16 *bih1 = conv[5], *bhh1 = conv[6], *Wl1 = conv[7],   *bl1 = conv[8],  *Wr1 = conv[9];
    const bf16 *Wp2 = conv[10], *bp2 = conv[11], *Wih2 = conv[12], *Whh2 = conv[13];
    const bf16 *bih2 = conv[14], *bhh2 = conv[15], *Wl2 = conv[16], *bl2 = conv[17], *Wr2 = conv[18];

    dim3 blk(256);
    const int gx = (N + 63) / 64;    // 782
    const int gl = (N + 31) / 32;    // 1563

    detect_dtype<<<dim3(1), dim3(64), 0, stream>>>((const unsigned short*)d_in[0], flag);
    convert_inputs<<<dim3(1024), blk, 0, stream>>>(ca, flag);

    // ---- layer 1 ----
    gemm_bias<8, true, false, false, false><<<dim3(gx, 1), blk, 0, stream>>>(
        xc, Wp1, bp1, nullptr, nullptr, nullptr, xp, nullptr, N, 128, 128);
    gemm_bias<8, false, true, false, false><<<dim3(gx, 4), blk, 0, stream>>>(
        xp, Wih1, bih1, bhh1, nullptr, nullptr, Y, nullptr, N, 512, 512);
    lstm_aggr<<<dim3(gl), blk, 0, stream>>>(Y, es, Whh1, aggr, N);
    gemm_bias<8, true, false, true, false><<<dim3(gx, 1), blk, 0, stream>>>(
        aggr, Wl1, bl1, nullptr, xc, Wr1, h1, nullptr, N, 128, 128);

    // ---- layer 2 ----
    gemm_bias<8, true, false, false, false><<<dim3(gx, 1), blk, 0, stream>>>(
        h1, Wp2, bp2, nullptr, nullptr, nullptr, xp, nullptr, N, 128, 128);
    gemm_bias<8, false, true, false, false><<<dim3(gx, 4), blk, 0, stream>>>(
        xp, Wih2, bih2, bhh2, nullptr, nullptr, Y, nullptr, N, 512, 512);
    lstm_aggr<<<dim3(gl), blk, 0, stream>>>(Y, es, Whh2, aggr, N);
    gemm_bias<3, false, false, true, true><<<dim3(gx, 1), blk, 0, stream>>>(
        aggr, Wl2, bl2, nullptr, h1, Wr2, d_out, flag, N, 40, 40);
}

// Round 7
// 782.359 us; speedup vs baseline: 1.1658x; 1.1658x over previous
//
#include <hip/hip_runtime.h>
#include <hip/hip_bf16.h>

// GCN_5016521802361: 2x SAGEConv(aggr='lstm', project=True), N=50000, D=16, F=128, C=40.
// Round 7: streaming Y-gather. Each wave DMAs whole 1KB Y rows into LDS via
// global_load_lds (uniform row base + lane*16B, fully coalesced, one request per
// 64B line, zero VGPR/VALU) instead of 16 scattered column-strip loads. Consumers
// read 8B gate-pieces from the LDS stage. 16-node blocks (r6 grouping was neutral).
// GEMMs: launch_bounds(256,2) + NCT=4 col-slices for 2x residency.

typedef __hip_bfloat16 bf16;
typedef __attribute__((ext_vector_type(8))) short short8;
typedef __attribute__((ext_vector_type(4))) short short4v;
typedef __attribute__((ext_vector_type(4))) float floatx4;

__device__ __forceinline__ float bf2f(bf16 v) { return __bfloat162float(v); }
__device__ __forceinline__ bf16  f2bf(float v) { return __float2bfloat16(v); }
__device__ __forceinline__ float bfs2f(short s) {
    union { float f; unsigned u; } v; v.u = ((unsigned)(unsigned short)s) << 16; return v.f;
}
__device__ __forceinline__ short f2bfs(float v) {
    bf16 b = __float2bfloat16(v); return *(short*)&b;
}

// merged-rcp LSTM cell update (r6, verified absmax-neutral)
__device__ __forceinline__ float cell(float i_, float f_, float g_, float o_, float& c) {
    float ei = __expf(-i_), ef = __expf(-f_), eg = __expf(2.f * g_);
    float cn = c * __builtin_amdgcn_rcpf(1.f + ef)
             + (eg - 1.f) * __builtin_amdgcn_rcpf((1.f + ei) * (eg + 1.f));
    c = cn;
    float ec = __expf(2.f * cn), eo = __expf(-o_);
    return (ec - 1.f) * __builtin_amdgcn_rcpf((ec + 1.f) * (1.f + eo));
}

// direct global->LDS DMA, 16B per lane (emits global_load_lds_dwordx4)
__device__ __forceinline__ void row_dma(const bf16* gp, void* lp) {
    __builtin_amdgcn_global_load_lds(
        (const __attribute__((address_space(1))) void*)gp,
        (__attribute__((address_space(3))) void*)lp, 16, 0, 0);
}

__global__ void detect_dtype(const unsigned short* __restrict__ xb, int* __restrict__ flag) {
    int cnt = 0;
    for (int i = threadIdx.x; i < 1024; i += 64) {
        int e = (xb[i] >> 7) & 0xFF;
        cnt += (e >= 0xC8);   // impossible exponent for N(0,1) bf16 data
    }
#pragma unroll
    for (int off = 32; off; off >>= 1) cnt += __shfl_down(cnt, off);
    if (threadIdx.x == 0) *flag = (cnt >= 16) ? 1 : 0;   // 1 => inputs are float32
}

struct Cvt { const void* src; bf16* dst; int n; };
struct CvtAll { Cvt t[19]; };

__global__ void convert_inputs(CvtAll ca, const int* __restrict__ flag) {
    const bool isf32 = (*flag != 0);
    const int stride = gridDim.x * blockDim.x;
    const int tid0 = blockIdx.x * blockDim.x + threadIdx.x;
#pragma unroll 1
    for (int k = 0; k < 19; k++) {
        const int n = ca.t[k].n;
        const float* sf = (const float*)ca.t[k].src;
        const bf16*  sb = (const bf16*)ca.t[k].src;
        bf16* d = ca.t[k].dst;
        for (int i = tid0; i < n; i += stride)
            d[i] = isf32 ? f2bf(sf[i]) : sb[i];
    }
}

template <int NCT, bool RELU, bool BIAS2, bool DUAL, bool OUTF>
__global__ __launch_bounds__(256, 2) void gemm_bias(
    const bf16* __restrict__ A, const bf16* __restrict__ B,
    const bf16* __restrict__ bias, const bf16* __restrict__ bias2,
    const bf16* __restrict__ A2, const bf16* __restrict__ B2,
    void* __restrict__ Cv, const int* __restrict__ oflag,
    int N, int nbt, int ldc)
{
    const int tid = threadIdx.x;
    const int w = tid >> 6, l = tid & 63, q = l >> 4, lid = l & 15;
    const int rowbase = blockIdx.x * 64 + w * 16;
    const int colslice = blockIdx.y * (NCT * 16);

    int arow = rowbase + lid;
    if (arow >= N) arow = N - 1;

    floatx4 acc[NCT];
#pragma unroll
    for (int ct = 0; ct < NCT; ct++) acc[ct] = (floatx4)(0.f);

    short8 bfrag[NCT][4];
#pragma unroll
    for (int ct = 0; ct < NCT; ct++) {
        int j = colslice + ct * 16 + lid;
        if (j >= nbt) j = nbt - 1;
#pragma unroll
        for (int kt = 0; kt < 4; kt++)
            bfrag[ct][kt] = *(const short8*)(B + (size_t)j * 128 + kt * 32 + q * 8);
    }
#pragma unroll
    for (int kt = 0; kt < 4; kt++) {
        short8 af = *(const short8*)(A + (size_t)arow * 128 + kt * 32 + q * 8);
#pragma unroll
        for (int ct = 0; ct < NCT; ct++)
            acc[ct] = __builtin_amdgcn_mfma_f32_16x16x32_bf16(af, bfrag[ct][kt], acc[ct], 0, 0, 0);
    }
    if constexpr (DUAL) {
#pragma unroll
        for (int ct = 0; ct < NCT; ct++) {
            int j = colslice + ct * 16 + lid;
            if (j >= nbt) j = nbt - 1;
#pragma unroll
            for (int kt = 0; kt < 4; kt++)
                bfrag[ct][kt] = *(const short8*)(B2 + (size_t)j * 128 + kt * 32 + q * 8);
        }
#pragma unroll
        for (int kt = 0; kt < 4; kt++) {
            short8 af = *(const short8*)(A2 + (size_t)arow * 128 + kt * 32 + q * 8);
#pragma unroll
            for (int ct = 0; ct < NCT; ct++)
                acc[ct] = __builtin_amdgcn_mfma_f32_16x16x32_bf16(af, bfrag[ct][kt], acc[ct], 0, 0, 0);
        }
    }
    bool of32 = false;
    if constexpr (OUTF) of32 = (*oflag != 0);
#pragma unroll
    for (int ct = 0; ct < NCT; ct++) {
        int cg = colslice + ct * 16 + lid;
        int cb = cg < nbt ? cg : nbt - 1;
        float bv = bf2f(bias[cb]);
        if constexpr (BIAS2) bv += bf2f(bias2[cb]);
#pragma unroll
        for (int r = 0; r < 4; r++) {
            int row = rowbase + q * 4 + r;
            float v = acc[ct][r] + bv;
            if constexpr (RELU) v = fmaxf(v, 0.f);
            if (row < N && cg < nbt) {
                size_t idx = (size_t)row * ldc + cg;
                if constexpr (OUTF) {
                    if (of32) ((float*)Cv)[idx] = v;
                    else      ((bf16*)Cv)[idx] = f2bf(v);
                } else {
                    ((bf16*)Cv)[idx] = f2bf(v);
                }
            }
        }
    }
}

// ---------------------------------------------------------------------------
// LSTM neighbor aggregation, transposed recurrence G^T = Whh * h^T.
// Block = 16 nodes, 256 thr (4 waves). Wave w owns hidden cols [32w,32w+32);
// Whh A-frags register-resident (128 regs). Per step: wave w DMAs 4 whole Y rows
// (srcl[t+1][4j+w], 1KB contiguous each) into the LDS stage via global_load_lds;
// consumers ds_read_b64 their gate pieces. Stage row stride 1040B breaks the
// power-of-2 bank pattern. One __syncthreads per step (drains the DMA).
// ---------------------------------------------------------------------------
__global__ __launch_bounds__(256, 2) void lstm_aggr(
    const bf16* __restrict__ Y,     // [N,512] pre-activations incl. both biases
    const int* __restrict__ esrc,   // [N,16]
    const bf16* __restrict__ Whh,   // [512,128]
    bf16* __restrict__ aggr,        // [N,128] out: final h
    int N)
{
    __shared__ alignas(16) short stage[2][16][520];  // 520 shorts = 1040B row stride
    __shared__ alignas(16) bf16 hb[2][16][136];
    __shared__ int srcl[16][16];    // [t][node]

    const int tid = threadIdx.x;
    const int w = tid >> 6, l = tid & 63, q = l >> 4, lid = l & 15;
    const int nodebase = blockIdx.x * 16;   // N = 50000 = 3125*16, exact

    {
        int node = tid >> 4, t = tid & 15;
        srcl[t][node] = esrc[(size_t)(nodebase + node) * 16 + t];
    }
    for (int i = tid; i < 16 * 136; i += 256) ((short*)hb[0])[i] = 0;

    // Whh A-fragments: wf[hl][g][kt]; A-row = gatecol = (2w+hl+8g)*16 + lid
    short8 wf[2][4][4];
#pragma unroll
    for (int hl = 0; hl < 2; hl++)
#pragma unroll
        for (int g = 0; g < 4; g++) {
            int gc = (2 * w + hl + 8 * g) * 16 + lid;
#pragma unroll
            for (int kt = 0; kt < 4; kt++)
                wf[hl][g][kt] = *(const short8*)(Whh + (size_t)gc * 128 + kt * 32 + q * 8);
        }

    float c[2][4];
#pragma unroll
    for (int hl = 0; hl < 2; hl++)
#pragma unroll
        for (int r = 0; r < 4; r++) c[hl][r] = 0.f;

    __syncthreads();   // srcl visible to all waves before first DMA

    // prologue: DMA t=0 rows into stage[0] (wave w fetches rows 4j+w)
#pragma unroll
    for (int j = 0; j < 4; j++) {
        int r = 4 * j + w;
        int s = srcl[0][r];
        row_dma(Y + (size_t)s * 512 + l * 8, &stage[0][r][0]);
    }

    __syncthreads();   // drains vmcnt: stage[0] landed; hb zero visible

#pragma unroll 2
    for (int t = 0; t < 16; t++) {
        const int cb = t & 1, nb = cb ^ 1;

        // issue DMA for t+1 first — in flight across the whole step
        if (t < 15) {
#pragma unroll
            for (int j = 0; j < 4; j++) {
                int r = 4 * j + w;
                int s = srcl[t + 1][r];
                row_dma(Y + (size_t)s * 512 + l * 8, &stage[nb][r][0]);
            }
        }

        // acc init from LDS stage: Y[s(lid)][(2w+hl+8g)*16 + 4q .. +3]
        floatx4 acc[2][4];
#pragma unroll
        for (int hl = 0; hl < 2; hl++)
#pragma unroll
            for (int g = 0; g < 4; g++) {
                short4v yv = *(const short4v*)&stage[cb][lid][(2 * w + hl + 8 * g) * 16 + 4 * q];
#pragma unroll
                for (int r = 0; r < 4; r++) acc[hl][g][r] = bfs2f(yv[r]);
            }

        // G^T += Whh * h^T : B-frag = h[node=lid][k] via ds_read_b128
#pragma unroll
        for (int kt = 0; kt < 4; kt++) {
            short8 bh = *(const short8*)&hb[cb][lid][kt * 32 + q * 8];
#pragma unroll
            for (int hl = 0; hl < 2; hl++)
#pragma unroll
                for (int g = 0; g < 4; g++)
                    acc[hl][g] = __builtin_amdgcn_mfma_f32_16x16x32_bf16(wf[hl][g][kt], bh, acc[hl][g], 0, 0, 0);
        }

        // gates; h' cols hc = 32w+16hl+q*4+r for node lid
#pragma unroll
        for (int hl = 0; hl < 2; hl++) {
            short4v hv;
#pragma unroll
            for (int r = 0; r < 4; r++)
                hv[r] = f2bfs(cell(acc[hl][0][r], acc[hl][1][r], acc[hl][2][r], acc[hl][3][r], c[hl][r]));
            if (t < 15) *(short4v*)&hb[nb][lid][32 * w + 16 * hl + 4 * q] = hv;
            else        *(short4v*)(aggr + (size_t)(nodebase + lid) * 128 + 32 * w + 16 * hl + 4 * q) = hv;
        }

        __syncthreads();   // orders hb swap AND guarantees t+1 DMA landed
    }
}

extern "C" void kernel_launch(void* const* d_in, const int* in_sizes, int n_in,
                              void* d_out, int out_size, void* d_ws, size_t ws_size,
                              hipStream_t stream)
{
    const int N = 50000;
    const int* es = (const int*)d_in[1];
    char* ws = (char*)d_ws;

    // converted bf16 copies of the 19 used float tensors @[0,15MB)
    static const int idxs[19] = {0, 8,9,10,11,12,13,14,15,16, 17,18,19,20,21,22,23,24,25};
    bf16* conv[19];
    size_t off = 0;
    CvtAll ca;
    for (int k = 0; k < 19; k++) {
        conv[k] = (bf16*)ws + off;
        ca.t[k].src = d_in[idxs[k]];
        ca.t[k].dst = conv[k];
        ca.t[k].n = in_sizes[idxs[k]];
        off += (size_t)((in_sizes[idxs[k]] + 63) & ~63);
    }
    int* flag = (int*)(ws + ((size_t)15 << 20));
    bf16* xp   = (bf16*)(ws + ((size_t)16 << 20));   // [N,128], reused as aggr
    bf16* Y    = (bf16*)(ws + ((size_t)30 << 20));   // [N,512]
    bf16* h1   = (bf16*)(ws + ((size_t)84 << 20));   // [N,128]
    bf16* aggr = xp;

    const bf16 *xc  = conv[0];
    const bf16 *Wp1 = conv[1],  *bp1 = conv[2],  *Wih1 = conv[3],  *Whh1 = conv[4];
    const bf16 *bih1 = conv[5], *bhh1 = conv[6], *Wl1 = conv[7],   *bl1 = conv[8],  *Wr1 = conv[9];
    const bf16 *Wp2 = conv[10], *bp2 = conv[11], *Wih2 = conv[12], *Whh2 = conv[13];
    const bf16 *bih2 = conv[14], *bhh2 = conv[15], *Wl2 = conv[16], *bl2 = conv[17], *Wr2 = conv[18];

    dim3 blk(256);
    const int gx = (N + 63) / 64;    // 782
    const int gl = N / 16;           // 3125 (exact)

    detect_dtype<<<dim3(1), dim3(64), 0, stream>>>((const unsigned short*)d_in[0], flag);
    convert_inputs<<<dim3(1024), blk, 0, stream>>>(ca, flag);

    // ---- layer 1 ----
    gemm_bias<4, true, false, false, false><<<dim3(gx, 2), blk, 0, stream>>>(
        xc, Wp1, bp1, nullptr, nullptr, nullptr, xp, nullptr, N, 128, 128);
    gemm_bias<4, false, true, false, false><<<dim3(gx, 8), blk, 0, stream>>>(
        xp, Wih1, bih1, bhh1, nullptr, nullptr, Y, nullptr, N, 512, 512);
    lstm_aggr<<<dim3(gl), blk, 0, stream>>>(Y, es, Whh1, aggr, N);
    gemm_bias<4, true, false, true, false><<<dim3(gx, 2), blk, 0, stream>>>(
        aggr, Wl1, bl1, nullptr, xc, Wr1, h1, nullptr, N, 128, 128);

    // ---- layer 2 ----
    gemm_bias<4, true, false, false, false><<<dim3(gx, 2), blk, 0, stream>>>(
        h1, Wp2, bp2, nullptr, nullptr, nullptr, xp, nullptr, N, 128, 128);
    gemm_bias<4, false, true, false, false><<<dim3(gx, 8), blk, 0, stream>>>(
        xp, Wih2, bih2, bhh2, nullptr, nullptr, Y, nullptr, N, 512, 512);
    lstm_aggr<<<dim3(gl), blk, 0, stream>>>(Y, es, Whh2, aggr, N);
    gemm_bias<3, false, false, true, true><<<dim3(gx, 1), blk, 0, stream>>>(
        aggr, Wl2, bl2, nullptr, h1, Wr2, d_out, flag, N, 40, 40);
}